// Round 8
// baseline (381.034 us; speedup 1.0000x reference)
//
#include <hip/hip_runtime.h>
#include <hip/hip_bf16.h>

#define IN_DIM 128
#define HID_DIM 256
#define OUT_DIM 40
#define SCAN_CHUNK 2048

typedef __attribute__((ext_vector_type(8))) __bf16 bf16x8;
typedef __attribute__((ext_vector_type(4))) float f32x4;

__device__ inline ushort f2bf(float f) {
    uint u = __builtin_bit_cast(uint, f);
    u = (u + 0x7fff + ((u >> 16) & 1)) >> 16;
    return (ushort)u;
}
__device__ inline float bfl(uint u) { return __builtin_bit_cast(float, u << 16); }
__device__ inline float bfh(uint u) { return __builtin_bit_cast(float, u & 0xffff0000u); }

// ---------------- input/weight conversion ----------------
__global__ __launch_bounds__(256) void cvt_x(const float* __restrict__ in,
                                             ushort* __restrict__ out, int n4) {
    int i = blockIdx.x * 256 + threadIdx.x;
    if (i < n4) {
        float4 v = ((const float4*)in)[i];
        uint2 o;
        o.x = (uint)f2bf(v.x) | ((uint)f2bf(v.y) << 16);
        o.y = (uint)f2bf(v.z) | ((uint)f2bf(v.w) << 16);
        ((uint2*)out)[i] = o;
    }
}

__global__ __launch_bounds__(256) void cvt_w2(const float* __restrict__ wl,
                                              const float* __restrict__ wr,
                                              ushort* __restrict__ ol,
                                              ushort* __restrict__ orr,
                                              int O, int OPAD, int K) {
    int idx = blockIdx.x * 256 + threadIdx.x;
    int tot = OPAD * K;
    if (idx >= tot) return;
    int row = idx / K;
    int col = idx - row * K;
    ushort vl = 0, vr = 0;
    if (row < O) {
        vl = f2bf(wl[row * K + col]);
        vr = f2bf(wr[row * K + col]);
    }
    ol[idx] = vl;
    orr[idx] = vr;
}

// ---------------- CSR build ----------------
__global__ __launch_bounds__(256) void hist_kernel(const int* __restrict__ dst,
                                                   int* __restrict__ cnt, int E) {
    int e = blockIdx.x * 256 + threadIdx.x;
    if (e < E) atomicAdd(&cnt[dst[e]], 1);
}

__global__ __launch_bounds__(256) void scan_pass1(const int* __restrict__ cnt,
                                                  int* __restrict__ bsum, int N) {
    __shared__ int red[256];
    const int base = blockIdx.x * SCAN_CHUNK;
    int s = 0;
    for (int i = threadIdx.x; i < SCAN_CHUNK; i += 256) {
        int idx = base + i;
        if (idx < N) s += cnt[idx];
    }
    red[threadIdx.x] = s;
    __syncthreads();
    for (int o = 128; o > 0; o >>= 1) {
        if (threadIdx.x < o) red[threadIdx.x] += red[threadIdx.x + o];
        __syncthreads();
    }
    if (threadIdx.x == 0) bsum[blockIdx.x] = red[0];
}

__global__ __launch_bounds__(256) void scan_pass2(int* __restrict__ bsum, int B) {
    __shared__ int ls[256];
    const int t = threadIdx.x;
    int v = (t < B) ? bsum[t] : 0;
    ls[t] = v;
    __syncthreads();
    for (int o = 1; o < 256; o <<= 1) {
        int u = (t >= o) ? ls[t - o] : 0;
        __syncthreads();
        ls[t] += u;
        __syncthreads();
    }
    if (t < B) bsum[t] = ls[t] - v;  // exclusive
}

__global__ __launch_bounds__(256) void scan_pass3(const int* __restrict__ cnt,
                                                  const int* __restrict__ bsum,
                                                  int* __restrict__ rowptr,
                                                  int* __restrict__ cursor,
                                                  float* __restrict__ inv, int N, int E) {
    __shared__ int ls[256];
    const int tbase = blockIdx.x * SCAN_CHUNK + threadIdx.x * 8;
    int c[8];
    int s = 0;
#pragma unroll
    for (int j = 0; j < 8; ++j) {
        int idx = tbase + j;
        c[j] = (idx < N) ? cnt[idx] : 0;
        s += c[j];
    }
    ls[threadIdx.x] = s;
    __syncthreads();
    for (int o = 1; o < 256; o <<= 1) {
        int u = (threadIdx.x >= o) ? ls[threadIdx.x - o] : 0;
        __syncthreads();
        ls[threadIdx.x] += u;
        __syncthreads();
    }
    int run = bsum[blockIdx.x] + ls[threadIdx.x] - s;
#pragma unroll
    for (int j = 0; j < 8; ++j) {
        int idx = tbase + j;
        if (idx < N) {
            rowptr[idx] = run;
            cursor[idx] = run;
            inv[idx] = 1.0f / fmaxf((float)c[j], 1.0f);
            run += c[j];
        }
    }
    if (blockIdx.x == 0 && threadIdx.x == 0) rowptr[N] = E;
}

__global__ __launch_bounds__(256) void fill_kernel(const int* __restrict__ src,
                                                   const int* __restrict__ dst,
                                                   int* __restrict__ cursor,
                                                   int* __restrict__ srcs, int E) {
    int e = blockIdx.x * 256 + threadIdx.x;
    if (e < E) {
        int pos = atomicAdd(&cursor[dst[e]], 1);
        srcs[pos] = src[e];
    }
}

// ---------------- gather mean (bf16 in/out, fp32 accumulate, 4-wide ILP) ----------------
template <int D>
__global__ __launch_bounds__(256) void gather_mean_bf(const ushort* __restrict__ feat,
                                                      const int* __restrict__ rowptr,
                                                      const int* __restrict__ srcs,
                                                      const float* __restrict__ inv,
                                                      ushort* __restrict__ out, int N) {
    constexpr int V = D / 64;  // bf16 per lane: 2 or 4
    const int wave = threadIdx.x >> 6;
    const int lane = threadIdx.x & 63;
    const int n = blockIdx.x * 4 + wave;
    if (n >= N) return;
    const int beg = rowptr[n];
    const int end = rowptr[n + 1];
    const int col = lane * V;
    float a0 = 0.f, a1 = 0.f, a2 = 0.f, a3 = 0.f;
    int e = beg;
    if constexpr (V == 4) {
        for (; e + 3 < end; e += 4) {
            int s0 = srcs[e], s1 = srcs[e + 1], s2 = srcs[e + 2], s3 = srcs[e + 3];
            uint2 q0 = *(const uint2*)&feat[(long long)s0 * D + col];
            uint2 q1 = *(const uint2*)&feat[(long long)s1 * D + col];
            uint2 q2 = *(const uint2*)&feat[(long long)s2 * D + col];
            uint2 q3 = *(const uint2*)&feat[(long long)s3 * D + col];
            a0 += (bfl(q0.x) + bfl(q1.x)) + (bfl(q2.x) + bfl(q3.x));
            a1 += (bfh(q0.x) + bfh(q1.x)) + (bfh(q2.x) + bfh(q3.x));
            a2 += (bfl(q0.y) + bfl(q1.y)) + (bfl(q2.y) + bfl(q3.y));
            a3 += (bfh(q0.y) + bfh(q1.y)) + (bfh(q2.y) + bfh(q3.y));
        }
        for (; e + 1 < end; e += 2) {
            int s0 = srcs[e], s1 = srcs[e + 1];
            uint2 q0 = *(const uint2*)&feat[(long long)s0 * D + col];
            uint2 q1 = *(const uint2*)&feat[(long long)s1 * D + col];
            a0 += bfl(q0.x) + bfl(q1.x);
            a1 += bfh(q0.x) + bfh(q1.x);
            a2 += bfl(q0.y) + bfl(q1.y);
            a3 += bfh(q0.y) + bfh(q1.y);
        }
        if (e < end) {
            uint2 q0 = *(const uint2*)&feat[(long long)srcs[e] * D + col];
            a0 += bfl(q0.x); a1 += bfh(q0.x); a2 += bfl(q0.y); a3 += bfh(q0.y);
        }
        const float sc = inv[n];
        uint2 o;
        o.x = (uint)f2bf(a0 * sc) | ((uint)f2bf(a1 * sc) << 16);
        o.y = (uint)f2bf(a2 * sc) | ((uint)f2bf(a3 * sc) << 16);
        *(uint2*)&out[(long long)n * D + col] = o;
    } else {
        for (; e + 3 < end; e += 4) {
            int s0 = srcs[e], s1 = srcs[e + 1], s2 = srcs[e + 2], s3 = srcs[e + 3];
            uint q0 = *(const uint*)&feat[(long long)s0 * D + col];
            uint q1 = *(const uint*)&feat[(long long)s1 * D + col];
            uint q2 = *(const uint*)&feat[(long long)s2 * D + col];
            uint q3 = *(const uint*)&feat[(long long)s3 * D + col];
            a0 += (bfl(q0) + bfl(q1)) + (bfl(q2) + bfl(q3));
            a1 += (bfh(q0) + bfh(q1)) + (bfh(q2) + bfh(q3));
        }
        for (; e + 1 < end; e += 2) {
            int s0 = srcs[e], s1 = srcs[e + 1];
            uint q0 = *(const uint*)&feat[(long long)s0 * D + col];
            uint q1 = *(const uint*)&feat[(long long)s1 * D + col];
            a0 += bfl(q0) + bfl(q1);
            a1 += bfh(q0) + bfh(q1);
        }
        if (e < end) {
            uint q0 = *(const uint*)&feat[(long long)srcs[e] * D + col];
            a0 += bfl(q0); a1 += bfh(q0);
        }
        const float sc = inv[n];
        uint o = (uint)f2bf(a0 * sc) | ((uint)f2bf(a1 * sc) << 16);
        *(uint*)&out[(long long)n * D + col] = o;
    }
}

// ---------------- MFMA SAGE GEMM (phase-fused K' = 2K, single barrier) ----------------
// out[m][o] = act( A'[m]·W'[o] + bias[o] ) with A' = [Amean|Aself], W' = [Wl|Wr].
// The entire W' tile (64 cols x 2K) is staged in LDS ONCE (one barrier per
// kernel), then the K'-loop is pure ds_read+MFMA with a rolling register
// prefetch of A fragments — no barriers to drain the load queue.
// 1-D grid swizzle: row = bx>>2, col = bx&3 so the 4 col-tiles of a row-block
// are dispatched adjacently and share A rows via L2/L3.
template <int K, bool RELU, bool OUTBF>
__global__ __launch_bounds__(256, 2) void sage_gemm_fused(const ushort* __restrict__ Amean,
                                                          const ushort* __restrict__ Aself,
                                                          const ushort* __restrict__ Wl,
                                                          const float* __restrict__ bias,
                                                          const ushort* __restrict__ Wr,
                                                          void* __restrict__ outv, int N, int O) {
    constexpr int K2 = 2 * K;
    constexpr int KP = K2 + 8;   // padded row: +16B -> 4-bank shift per row, conflict-free
    constexpr int NK = K2 / 32;  // fused k-steps
    __shared__ __align__(16) ushort Ws[64 * KP];

    const int tid = threadIdx.x;
    const int wave = tid >> 6;
    const int lane = tid & 63;
    const int ln = lane & 15;
    const int quad = lane >> 4;
    const int bm0 = (blockIdx.x >> 2) * 128;
    const int bn0 = (blockIdx.x & 3) * 64;

    int arow[2];
#pragma unroll
    for (int rt = 0; rt < 2; ++rt) {
        int r = bm0 + wave * 32 + rt * 16 + ln;
        arow[rt] = min(r, N - 1);
    }

    // stage W' = [Wl | Wr] (single LDS fill, one barrier total)
#pragma unroll
    for (int i = tid; i < 64 * (K / 8); i += 256) {
        int row = i / (K / 8);
        int c8 = (i % (K / 8)) * 8;
        *(ulonglong2*)&Ws[row * KP + c8] =
            *(const ulonglong2*)&Wl[(long long)(bn0 + row) * K + c8];
        *(ulonglong2*)&Ws[row * KP + K + c8] =
            *(const ulonglong2*)&Wr[(long long)(bn0 + row) * K + c8];
    }

    f32x4 acc[2][4] = {};
    bf16x8 a_cur[2], a_nxt[2];
#pragma unroll
    for (int rt = 0; rt < 2; ++rt)
        a_cur[rt] = *(const bf16x8*)&Amean[(long long)arow[rt] * K + quad * 8];

    __syncthreads();

#pragma unroll
    for (int kk = 0; kk < NK; ++kk) {
        if (kk + 1 < NK) {
            const ushort* __restrict__ An = (kk + 1 < NK / 2) ? Amean : Aself;
            const int ko = ((kk + 1) % (NK / 2)) * 32;
#pragma unroll
            for (int rt = 0; rt < 2; ++rt)
                a_nxt[rt] = *(const bf16x8*)&An[(long long)arow[rt] * K + ko + quad * 8];
        }
#pragma unroll
        for (int ct = 0; ct < 4; ++ct) {
            bf16x8 b = *(const bf16x8*)&Ws[(ct * 16 + ln) * KP + kk * 32 + quad * 8];
#pragma unroll
            for (int rt = 0; rt < 2; ++rt)
                acc[rt][ct] = __builtin_amdgcn_mfma_f32_16x16x32_bf16(a_cur[rt], b, acc[rt][ct], 0, 0, 0);
        }
#pragma unroll
        for (int rt = 0; rt < 2; ++rt) a_cur[rt] = a_nxt[rt];
    }

    // epilogue: C/D layout col=lane&15, row=quad*4+reg
#pragma unroll
    for (int rt = 0; rt < 2; ++rt) {
        int rbase = bm0 + wave * 32 + rt * 16 + quad * 4;
#pragma unroll
        for (int ct = 0; ct < 4; ++ct) {
            int col = bn0 + ct * 16 + ln;
            if (col >= O) continue;
            float bv = bias[col];
#pragma unroll
            for (int r = 0; r < 4; ++r) {
                int row = rbase + r;
                if (row >= N) continue;
                float v = acc[rt][ct][r] + bv;
                if (RELU) v = fmaxf(v, 0.f);
                if (OUTBF)
                    ((ushort*)outv)[(long long)row * O + col] = f2bf(v);
                else
                    ((float*)outv)[(long long)row * O + col] = v;
            }
        }
    }
}

// ---------------- layer-3 pre-aggregation GEMM: P = A@Wl^T (bf16), S = A@Wr^T (fp32) ----------------
// 64-row blocks; the wave's full A strip lives in 32 VGPRs; both W tiles
// staged once (single barrier); zero barriers afterwards.
template <int K>
__global__ __launch_bounds__(256, 2) void sage_gemm_pre(const ushort* __restrict__ A0,
                                                        const ushort* __restrict__ Wl,
                                                        const ushort* __restrict__ Wr,
                                                        ushort* __restrict__ P,
                                                        float* __restrict__ S, int N, int O) {
    constexpr int KP = 2 * K + 8;
    constexpr int NK = K / 32;  // 8
    __shared__ __align__(16) ushort Ws[64 * KP];

    const int tid = threadIdx.x;
    const int wave = tid >> 6;
    const int lane = tid & 63;
    const int ln = lane & 15;
    const int quad = lane >> 4;
    const int bm0 = blockIdx.x * 64;

    const int arow = min(bm0 + wave * 16 + ln, N - 1);

    // full A strip in registers (8 independent loads in flight)
    bf16x8 areg[NK];
#pragma unroll
    for (int kk = 0; kk < NK; ++kk)
        areg[kk] = *(const bf16x8*)&A0[(long long)arow * K + kk * 32 + quad * 8];

    // stage both W tiles: Wl -> cols [0,K), Wr -> [K,2K)
#pragma unroll
    for (int i = tid; i < 64 * (K / 8); i += 256) {
        int row = i / (K / 8);
        int c8 = (i % (K / 8)) * 8;
        *(ulonglong2*)&Ws[row * KP + c8] =
            *(const ulonglong2*)&Wl[(long long)row * K + c8];
        *(ulonglong2*)&Ws[row * KP + K + c8] =
            *(const ulonglong2*)&Wr[(long long)row * K + c8];
    }
    __syncthreads();

#pragma unroll
    for (int phase = 0; phase < 2; ++phase) {
        f32x4 acc[4] = {};
#pragma unroll
        for (int kk = 0; kk < NK; ++kk) {
#pragma unroll
            for (int ct = 0; ct < 4; ++ct) {
                bf16x8 b = *(const bf16x8*)&Ws[(ct * 16 + ln) * KP + phase * K + kk * 32 + quad * 8];
                acc[ct] = __builtin_amdgcn_mfma_f32_16x16x32_bf16(areg[kk], b, acc[ct], 0, 0, 0);
            }
        }
        int rbase = bm0 + wave * 16 + quad * 4;
#pragma unroll
        for (int ct = 0; ct < 3; ++ct) {  // cols >= 48 are padding
            int col = ct * 16 + ln;
            if (col >= O) continue;
#pragma unroll
            for (int r = 0; r < 4; ++r) {
                int row = rbase + r;
                if (row >= N) continue;
                if (phase == 0)
                    P[(long long)row * O + col] = f2bf(acc[ct][r]);
                else
                    S[(long long)row * O + col] = acc[ct][r];
            }
        }
    }
}

// ---------------- fused mean-agg(D=40) + self + bias + log_softmax ----------------
__global__ __launch_bounds__(256) void agg_bias_lsm(const ushort* __restrict__ P,
                                                    const float* __restrict__ S,
                                                    const float* __restrict__ bias,
                                                    const int* __restrict__ rowptr,
                                                    const int* __restrict__ srcs,
                                                    const float* __restrict__ inv,
                                                    float* __restrict__ out, int N) {
    const int wave = threadIdx.x >> 6;
    const int lane = threadIdx.x & 63;
    const int n = blockIdx.x * 4 + wave;
    if (n >= N) return;
    const int beg = rowptr[n];
    const int end = rowptr[n + 1];
    const bool act = lane < OUT_DIM;
    const int cidx = act ? lane : 0;

    float acc = 0.f;
    int e = beg;
    for (; e + 3 < end; e += 4) {
        int s0 = srcs[e], s1 = srcs[e + 1], s2 = srcs[e + 2], s3 = srcs[e + 3];
        float v0 = __builtin_bit_cast(float, (uint)P[(long long)s0 * OUT_DIM + cidx] << 16);
        float v1 = __builtin_bit_cast(float, (uint)P[(long long)s1 * OUT_DIM + cidx] << 16);
        float v2 = __builtin_bit_cast(float, (uint)P[(long long)s2 * OUT_DIM + cidx] << 16);
        float v3 = __builtin_bit_cast(float, (uint)P[(long long)s3 * OUT_DIM + cidx] << 16);
        acc += (v0 + v1) + (v2 + v3);
    }
    for (; e < end; ++e)
        acc += __builtin_bit_cast(float, (uint)P[(long long)srcs[e] * OUT_DIM + cidx] << 16);

    float v = act ? (acc * inv[n] + S[(long long)n * OUT_DIM + lane] + bias[lane]) : -INFINITY;
    float m = v;
#pragma unroll
    for (int o = 32; o > 0; o >>= 1) m = fmaxf(m, __shfl_xor(m, o, 64));
    float ex = act ? expf(v - m) : 0.f;
    float sm = ex;
#pragma unroll
    for (int o = 32; o > 0; o >>= 1) sm += __shfl_xor(sm, o, 64);
    float ls = logf(sm);
    if (act) out[(long long)n * OUT_DIM + lane] = v - m - ls;
}

extern "C" void kernel_launch(void* const* d_in, const int* in_sizes, int n_in,
                              void* d_out, int out_size, void* d_ws, size_t ws_size,
                              hipStream_t stream) {
    const float* x   = (const float*)d_in[0];
    const int*   ei  = (const int*)d_in[1];
    const float* Wl1 = (const float*)d_in[2];
    const float* bl1 = (const float*)d_in[3];
    const float* Wr1 = (const float*)d_in[4];
    const float* Wl2 = (const float*)d_in[5];
    const float* bl2 = (const float*)d_in[6];
    const float* Wr2 = (const float*)d_in[7];
    const float* Wl3 = (const float*)d_in[8];
    const float* bl3 = (const float*)d_in[9];
    const float* Wr3 = (const float*)d_in[10];
    float* out = (float*)d_out;

    const int N = in_sizes[0] / IN_DIM;  // 50000
    const int E = in_sizes[1] / 2;       // 600000
    const int* src = ei;
    const int* dst = ei + E;

    // ---- workspace layout ----
    char* w = (char*)d_ws;
    size_t off = 0;
    auto alloc = [&](size_t bytes) {
        void* p = w + off;
        off = (off + bytes + 255) & ~(size_t)255;
        return p;
    };
    ushort* xb   = (ushort*)alloc((size_t)N * IN_DIM * 2);
    ushort* M    = (ushort*)alloc((size_t)N * HID_DIM * 2);
    ushort* H1   = (ushort*)alloc((size_t)N * HID_DIM * 2);
    ushort* H2   = (ushort*)alloc((size_t)N * HID_DIM * 2);
    ushort* P3   = (ushort*)alloc((size_t)N * OUT_DIM * 2);
    float*  S3   = (float*)alloc((size_t)N * OUT_DIM * 4);
    float*  inv  = (float*)alloc((size_t)N * 4);
    int*    cnt  = (int*)alloc((size_t)N * 4);
    int*    rowptr = (int*)alloc((size_t)(N + 1) * 4);
    int*    cursor = (int*)alloc((size_t)N * 4);
    int*    srcs = (int*)alloc((size_t)E * 4);
    int*    bsum = (int*)alloc(256 * 4);
    ushort* Wl1b = (ushort*)alloc(256 * 128 * 2);
    ushort* Wr1b = (ushort*)alloc(256 * 128 * 2);
    ushort* Wl2b = (ushort*)alloc(256 * 256 * 2);
    ushort* Wr2b = (ushort*)alloc(256 * 256 * 2);
    ushort* Wl3b = (ushort*)alloc(64 * 256 * 2);
    ushort* Wr3b = (ushort*)alloc(64 * 256 * 2);

    // ---- conversions ----
    cvt_x<<<(N * IN_DIM / 4 + 255) / 256, 256, 0, stream>>>(x, xb, N * IN_DIM / 4);
    cvt_w2<<<(256 * 128 + 255) / 256, 256, 0, stream>>>(Wl1, Wr1, Wl1b, Wr1b, 256, 256, 128);
    cvt_w2<<<(256 * 256 + 255) / 256, 256, 0, stream>>>(Wl2, Wr2, Wl2b, Wr2b, 256, 256, 256);
    cvt_w2<<<(64 * 256 + 255) / 256, 256, 0, stream>>>(Wl3, Wr3, Wl3b, Wr3b, 40, 64, 256);

    // ---- CSR build (parallel 3-pass scan) ----
    const int SB = (N + SCAN_CHUNK - 1) / SCAN_CHUNK;  // 25
    hipMemsetAsync(cnt, 0, (size_t)N * sizeof(int), stream);
    hist_kernel<<<(E + 255) / 256, 256, 0, stream>>>(dst, cnt, E);
    scan_pass1<<<SB, 256, 0, stream>>>(cnt, bsum, N);
    scan_pass2<<<1, 256, 0, stream>>>(bsum, SB);
    scan_pass3<<<SB, 256, 0, stream>>>(cnt, bsum, rowptr, cursor, inv, N, E);
    fill_kernel<<<(E + 255) / 256, 256, 0, stream>>>(src, dst, cursor, srcs, E);

    const int gm = (N + 127) / 128;  // 391
    const int gg = (N + 3) / 4;

    // ---- layer 1: K=128 -> 256, relu ----
    gather_mean_bf<IN_DIM><<<gg, 256, 0, stream>>>(xb, rowptr, srcs, inv, M, N);
    sage_gemm_fused<IN_DIM, true, true><<<gm * 4, 256, 0, stream>>>(
        M, xb, Wl1b, bl1, Wr1b, H1, N, HID_DIM);

    // ---- layer 2: K=256 -> 256, relu ----
    gather_mean_bf<HID_DIM><<<gg, 256, 0, stream>>>(H1, rowptr, srcs, inv, M, N);
    sage_gemm_fused<HID_DIM, true, true><<<gm * 4, 256, 0, stream>>>(
        M, H1, Wl2b, bl2, Wr2b, H2, N, HID_DIM);

    // ---- layer 3 (GEMM-first): P3 = H2@Wl3^T, S3 = H2@Wr3^T, then fused agg+lsm ----
    sage_gemm_pre<HID_DIM><<<(N + 63) / 64, 256, 0, stream>>>(
        H2, Wl3b, Wr3b, P3, S3, N, OUT_DIM);
    agg_bias_lsm<<<gg, 256, 0, stream>>>(P3, S3, bl3, rowptr, srcs, inv, out, N);
}

// Round 9
// 368.481 us; speedup vs baseline: 1.0341x; 1.0341x over previous
//
#include <hip/hip_runtime.h>
#include <hip/hip_bf16.h>

#define IN_DIM 128
#define HID_DIM 256
#define OUT_DIM 40
#define SCAN_CHUNK 2048

typedef __attribute__((ext_vector_type(8))) __bf16 bf16x8;
typedef __attribute__((ext_vector_type(4))) float f32x4;

__device__ inline ushort f2bf(float f) {
    uint u = __builtin_bit_cast(uint, f);
    u = (u + 0x7fff + ((u >> 16) & 1)) >> 16;
    return (ushort)u;
}
__device__ inline float bfl(uint u) { return __builtin_bit_cast(float, u << 16); }
__device__ inline float bfh(uint u) { return __builtin_bit_cast(float, u & 0xffff0000u); }

// ---------------- input/weight conversion ----------------
__global__ __launch_bounds__(256) void cvt_x(const float* __restrict__ in,
                                             ushort* __restrict__ out, int n4) {
    int i = blockIdx.x * 256 + threadIdx.x;
    if (i < n4) {
        float4 v = ((const float4*)in)[i];
        uint2 o;
        o.x = (uint)f2bf(v.x) | ((uint)f2bf(v.y) << 16);
        o.y = (uint)f2bf(v.z) | ((uint)f2bf(v.w) << 16);
        ((uint2*)out)[i] = o;
    }
}

__global__ __launch_bounds__(256) void cvt_w2(const float* __restrict__ wl,
                                              const float* __restrict__ wr,
                                              ushort* __restrict__ ol,
                                              ushort* __restrict__ orr,
                                              int O, int OPAD, int K) {
    int idx = blockIdx.x * 256 + threadIdx.x;
    int tot = OPAD * K;
    if (idx >= tot) return;
    int row = idx / K;
    int col = idx - row * K;
    ushort vl = 0, vr = 0;
    if (row < O) {
        vl = f2bf(wl[row * K + col]);
        vr = f2bf(wr[row * K + col]);
    }
    ol[idx] = vl;
    orr[idx] = vr;
}

// ---------------- CSR build ----------------
__global__ __launch_bounds__(256) void hist_kernel(const int* __restrict__ dst,
                                                   int* __restrict__ cnt, int E) {
    int e = blockIdx.x * 256 + threadIdx.x;
    if (e < E) atomicAdd(&cnt[dst[e]], 1);
}

__global__ __launch_bounds__(256) void scan_pass1(const int* __restrict__ cnt,
                                                  int* __restrict__ bsum, int N) {
    __shared__ int red[256];
    const int base = blockIdx.x * SCAN_CHUNK;
    int s = 0;
    for (int i = threadIdx.x; i < SCAN_CHUNK; i += 256) {
        int idx = base + i;
        if (idx < N) s += cnt[idx];
    }
    red[threadIdx.x] = s;
    __syncthreads();
    for (int o = 128; o > 0; o >>= 1) {
        if (threadIdx.x < o) red[threadIdx.x] += red[threadIdx.x + o];
        __syncthreads();
    }
    if (threadIdx.x == 0) bsum[blockIdx.x] = red[0];
}

__global__ __launch_bounds__(256) void scan_pass2(int* __restrict__ bsum, int B) {
    __shared__ int ls[256];
    const int t = threadIdx.x;
    int v = (t < B) ? bsum[t] : 0;
    ls[t] = v;
    __syncthreads();
    for (int o = 1; o < 256; o <<= 1) {
        int u = (t >= o) ? ls[t - o] : 0;
        __syncthreads();
        ls[t] += u;
        __syncthreads();
    }
    if (t < B) bsum[t] = ls[t] - v;  // exclusive
}

__global__ __launch_bounds__(256) void scan_pass3(const int* __restrict__ cnt,
                                                  const int* __restrict__ bsum,
                                                  int* __restrict__ rowptr,
                                                  int* __restrict__ cursor,
                                                  float* __restrict__ inv, int N, int E) {
    __shared__ int ls[256];
    const int tbase = blockIdx.x * SCAN_CHUNK + threadIdx.x * 8;
    int c[8];
    int s = 0;
#pragma unroll
    for (int j = 0; j < 8; ++j) {
        int idx = tbase + j;
        c[j] = (idx < N) ? cnt[idx] : 0;
        s += c[j];
    }
    ls[threadIdx.x] = s;
    __syncthreads();
    for (int o = 1; o < 256; o <<= 1) {
        int u = (threadIdx.x >= o) ? ls[threadIdx.x - o] : 0;
        __syncthreads();
        ls[threadIdx.x] += u;
        __syncthreads();
    }
    int run = bsum[blockIdx.x] + ls[threadIdx.x] - s;
#pragma unroll
    for (int j = 0; j < 8; ++j) {
        int idx = tbase + j;
        if (idx < N) {
            rowptr[idx] = run;
            cursor[idx] = run;
            inv[idx] = 1.0f / fmaxf((float)c[j], 1.0f);
            run += c[j];
        }
    }
    if (blockIdx.x == 0 && threadIdx.x == 0) rowptr[N] = E;
}

__global__ __launch_bounds__(256) void fill_kernel(const int* __restrict__ src,
                                                   const int* __restrict__ dst,
                                                   int* __restrict__ cursor,
                                                   int* __restrict__ srcs, int E) {
    int e = blockIdx.x * 256 + threadIdx.x;
    if (e < E) {
        int pos = atomicAdd(&cursor[dst[e]], 1);
        srcs[pos] = src[e];
    }
}

// ---------------- gather mean (bf16 in/out, fp32 accumulate, 4-wide ILP) ----------------
template <int D>
__global__ __launch_bounds__(256) void gather_mean_bf(const ushort* __restrict__ feat,
                                                      const int* __restrict__ rowptr,
                                                      const int* __restrict__ srcs,
                                                      const float* __restrict__ inv,
                                                      ushort* __restrict__ out, int N) {
    constexpr int V = D / 64;  // bf16 per lane: 2 or 4
    const int wave = threadIdx.x >> 6;
    const int lane = threadIdx.x & 63;
    const int n = blockIdx.x * 4 + wave;
    if (n >= N) return;
    const int beg = rowptr[n];
    const int end = rowptr[n + 1];
    const int col = lane * V;
    float a0 = 0.f, a1 = 0.f, a2 = 0.f, a3 = 0.f;
    int e = beg;
    if constexpr (V == 4) {
        for (; e + 3 < end; e += 4) {
            int s0 = srcs[e], s1 = srcs[e + 1], s2 = srcs[e + 2], s3 = srcs[e + 3];
            uint2 q0 = *(const uint2*)&feat[(long long)s0 * D + col];
            uint2 q1 = *(const uint2*)&feat[(long long)s1 * D + col];
            uint2 q2 = *(const uint2*)&feat[(long long)s2 * D + col];
            uint2 q3 = *(const uint2*)&feat[(long long)s3 * D + col];
            a0 += (bfl(q0.x) + bfl(q1.x)) + (bfl(q2.x) + bfl(q3.x));
            a1 += (bfh(q0.x) + bfh(q1.x)) + (bfh(q2.x) + bfh(q3.x));
            a2 += (bfl(q0.y) + bfl(q1.y)) + (bfl(q2.y) + bfl(q3.y));
            a3 += (bfh(q0.y) + bfh(q1.y)) + (bfh(q2.y) + bfh(q3.y));
        }
        for (; e + 1 < end; e += 2) {
            int s0 = srcs[e], s1 = srcs[e + 1];
            uint2 q0 = *(const uint2*)&feat[(long long)s0 * D + col];
            uint2 q1 = *(const uint2*)&feat[(long long)s1 * D + col];
            a0 += bfl(q0.x) + bfl(q1.x);
            a1 += bfh(q0.x) + bfh(q1.x);
            a2 += bfl(q0.y) + bfl(q1.y);
            a3 += bfh(q0.y) + bfh(q1.y);
        }
        if (e < end) {
            uint2 q0 = *(const uint2*)&feat[(long long)srcs[e] * D + col];
            a0 += bfl(q0.x); a1 += bfh(q0.x); a2 += bfl(q0.y); a3 += bfh(q0.y);
        }
        const float sc = inv[n];
        uint2 o;
        o.x = (uint)f2bf(a0 * sc) | ((uint)f2bf(a1 * sc) << 16);
        o.y = (uint)f2bf(a2 * sc) | ((uint)f2bf(a3 * sc) << 16);
        *(uint2*)&out[(long long)n * D + col] = o;
    } else {
        for (; e + 3 < end; e += 4) {
            int s0 = srcs[e], s1 = srcs[e + 1], s2 = srcs[e + 2], s3 = srcs[e + 3];
            uint q0 = *(const uint*)&feat[(long long)s0 * D + col];
            uint q1 = *(const uint*)&feat[(long long)s1 * D + col];
            uint q2 = *(const uint*)&feat[(long long)s2 * D + col];
            uint q3 = *(const uint*)&feat[(long long)s3 * D + col];
            a0 += (bfl(q0) + bfl(q1)) + (bfl(q2) + bfl(q3));
            a1 += (bfh(q0) + bfh(q1)) + (bfh(q2) + bfh(q3));
        }
        for (; e + 1 < end; e += 2) {
            int s0 = srcs[e], s1 = srcs[e + 1];
            uint q0 = *(const uint*)&feat[(long long)s0 * D + col];
            uint q1 = *(const uint*)&feat[(long long)s1 * D + col];
            a0 += bfl(q0) + bfl(q1);
            a1 += bfh(q0) + bfh(q1);
        }
        if (e < end) {
            uint q0 = *(const uint*)&feat[(long long)srcs[e] * D + col];
            a0 += bfl(q0); a1 += bfh(q0);
        }
        const float sc = inv[n];
        uint o = (uint)f2bf(a0 * sc) | ((uint)f2bf(a1 * sc) << 16);
        *(uint*)&out[(long long)n * D + col] = o;
    }
}

// ---------------- MFMA SAGE GEMM (per-phase W in LDS; A strip prefetched in the
// barrier-free zone AFTER the staging barrier so all 16 loads stay in flight) ----------------
template <int K, bool RELU, bool OUTBF>
__global__ __launch_bounds__(256, 3) void sage_gemm_mfma(const ushort* __restrict__ Amean,
                                                         const ushort* __restrict__ Aself,
                                                         const ushort* __restrict__ Wl,
                                                         const float* __restrict__ bias,
                                                         const ushort* __restrict__ Wr,
                                                         void* __restrict__ outv, int N, int O) {
    constexpr int KP = K + 8;   // padded LDS row (conflict-free ds_read_b128)
    constexpr int NK = K / 32;  // k-steps per phase
    __shared__ __align__(16) ushort Ws[64 * KP];

    const int tid = threadIdx.x;
    const int wave = tid >> 6;
    const int lane = tid & 63;
    const int ln = lane & 15;
    const int quad = lane >> 4;
    const int bm0 = blockIdx.x * 128;
    const int bn0 = blockIdx.y * 64;

    int arow[2];
#pragma unroll
    for (int rt = 0; rt < 2; ++rt) {
        int r = bm0 + wave * 32 + rt * 16 + ln;
        arow[rt] = min(r, N - 1);
    }

    f32x4 acc[2][4] = {};

    for (int phase = 0; phase < 2; ++phase) {
        const ushort* __restrict__ A = phase ? Aself : Amean;
        const ushort* __restrict__ W = phase ? Wr : Wl;

        __syncthreads();  // Ws reuse guard
#pragma unroll
        for (int i = tid; i < 64 * (K / 8); i += 256) {
            int row = i / (K / 8);
            int c8 = (i % (K / 8)) * 8;
            *(ulonglong2*)&Ws[row * KP + c8] =
                *(const ulonglong2*)&W[(long long)(bn0 + row) * K + c8];
        }
        __syncthreads();  // drains staging; nothing else outstanding

        // ---- barrier-free zone: issue the whole A strip, then consume ----
        bf16x8 areg[NK][2];
#pragma unroll
        for (int kk = 0; kk < NK; ++kk)
#pragma unroll
            for (int rt = 0; rt < 2; ++rt)
                areg[kk][rt] = *(const bf16x8*)&A[(long long)arow[rt] * K + kk * 32 + quad * 8];

#pragma unroll
        for (int kk = 0; kk < NK; ++kk) {
#pragma unroll
            for (int ct = 0; ct < 4; ++ct) {
                bf16x8 b = *(const bf16x8*)&Ws[(ct * 16 + ln) * KP + kk * 32 + quad * 8];
#pragma unroll
                for (int rt = 0; rt < 2; ++rt)
                    acc[rt][ct] = __builtin_amdgcn_mfma_f32_16x16x32_bf16(areg[kk][rt], b, acc[rt][ct], 0, 0, 0);
            }
        }
    }

    // epilogue: C/D layout col=lane&15, row=quad*4+reg
#pragma unroll
    for (int rt = 0; rt < 2; ++rt) {
        int rbase = bm0 + wave * 32 + rt * 16 + quad * 4;
#pragma unroll
        for (int ct = 0; ct < 4; ++ct) {
            int col = bn0 + ct * 16 + ln;
            if (col >= O) continue;
            float bv = bias[col];
#pragma unroll
            for (int r = 0; r < 4; ++r) {
                int row = rbase + r;
                if (row >= N) continue;
                float v = acc[rt][ct][r] + bv;
                if (RELU) v = fmaxf(v, 0.f);
                if (OUTBF)
                    ((ushort*)outv)[(long long)row * O + col] = f2bf(v);
                else
                    ((float*)outv)[(long long)row * O + col] = v;
            }
        }
    }
}

// ---------------- layer-3 pre-aggregation GEMM: P = A@Wl^T (bf16), S = A@Wr^T (fp32) ----------------
// O padded to 48 (3 col-tiles). Both W tiles staged once -> single barrier;
// A strip loaded AFTER the barrier (stays in flight); zero barriers after.
template <int K>
__global__ __launch_bounds__(256, 3) void sage_gemm_pre(const ushort* __restrict__ A0,
                                                        const ushort* __restrict__ Wl,
                                                        const ushort* __restrict__ Wr,
                                                        ushort* __restrict__ P,
                                                        float* __restrict__ S, int N, int O) {
    constexpr int KP = 2 * K + 8;
    constexpr int NK = K / 32;  // 8
    __shared__ __align__(16) ushort Ws[48 * KP];  // 49 KB

    const int tid = threadIdx.x;
    const int wave = tid >> 6;
    const int lane = tid & 63;
    const int ln = lane & 15;
    const int quad = lane >> 4;
    const int bm0 = blockIdx.x * 64;

    const int arow = min(bm0 + wave * 16 + ln, N - 1);

    // stage both W tiles: Wl -> cols [0,K), Wr -> [K,2K); 48 rows
#pragma unroll
    for (int i = tid; i < 48 * (K / 8); i += 256) {
        int row = i / (K / 8);
        int c8 = (i % (K / 8)) * 8;
        *(ulonglong2*)&Ws[row * KP + c8] =
            *(const ulonglong2*)&Wl[(long long)row * K + c8];
        *(ulonglong2*)&Ws[row * KP + K + c8] =
            *(const ulonglong2*)&Wr[(long long)row * K + c8];
    }
    __syncthreads();

    // barrier-free zone: full A strip (8 loads in flight), reused by both phases
    bf16x8 areg[NK];
#pragma unroll
    for (int kk = 0; kk < NK; ++kk)
        areg[kk] = *(const bf16x8*)&A0[(long long)arow * K + kk * 32 + quad * 8];

#pragma unroll
    for (int phase = 0; phase < 2; ++phase) {
        f32x4 acc[3] = {};
#pragma unroll
        for (int kk = 0; kk < NK; ++kk) {
#pragma unroll
            for (int ct = 0; ct < 3; ++ct) {
                bf16x8 b = *(const bf16x8*)&Ws[(ct * 16 + ln) * KP + phase * K + kk * 32 + quad * 8];
                acc[ct] = __builtin_amdgcn_mfma_f32_16x16x32_bf16(areg[kk], b, acc[ct], 0, 0, 0);
            }
        }
        int rbase = bm0 + wave * 16 + quad * 4;
#pragma unroll
        for (int ct = 0; ct < 3; ++ct) {
            int col = ct * 16 + ln;
            if (col >= O) continue;
#pragma unroll
            for (int r = 0; r < 4; ++r) {
                int row = rbase + r;
                if (row >= N) continue;
                if (phase == 0)
                    P[(long long)row * O + col] = f2bf(acc[ct][r]);
                else
                    S[(long long)row * O + col] = acc[ct][r];
            }
        }
    }
}

// ---------------- fused mean-agg(D=40) + self + bias + log_softmax ----------------
__global__ __launch_bounds__(256) void agg_bias_lsm(const ushort* __restrict__ P,
                                                    const float* __restrict__ S,
                                                    const float* __restrict__ bias,
                                                    const int* __restrict__ rowptr,
                                                    const int* __restrict__ srcs,
                                                    const float* __restrict__ inv,
                                                    float* __restrict__ out, int N) {
    const int wave = threadIdx.x >> 6;
    const int lane = threadIdx.x & 63;
    const int n = blockIdx.x * 4 + wave;
    if (n >= N) return;
    const int beg = rowptr[n];
    const int end = rowptr[n + 1];
    const bool act = lane < OUT_DIM;
    const int cidx = act ? lane : 0;

    float acc = 0.f;
    int e = beg;
    for (; e + 3 < end; e += 4) {
        int s0 = srcs[e], s1 = srcs[e + 1], s2 = srcs[e + 2], s3 = srcs[e + 3];
        float v0 = __builtin_bit_cast(float, (uint)P[(long long)s0 * OUT_DIM + cidx] << 16);
        float v1 = __builtin_bit_cast(float, (uint)P[(long long)s1 * OUT_DIM + cidx] << 16);
        float v2 = __builtin_bit_cast(float, (uint)P[(long long)s2 * OUT_DIM + cidx] << 16);
        float v3 = __builtin_bit_cast(float, (uint)P[(long long)s3 * OUT_DIM + cidx] << 16);
        acc += (v0 + v1) + (v2 + v3);
    }
    for (; e < end; ++e)
        acc += __builtin_bit_cast(float, (uint)P[(long long)srcs[e] * OUT_DIM + cidx] << 16);

    float v = act ? (acc * inv[n] + S[(long long)n * OUT_DIM + lane] + bias[lane]) : -INFINITY;
    float m = v;
#pragma unroll
    for (int o = 32; o > 0; o >>= 1) m = fmaxf(m, __shfl_xor(m, o, 64));
    float ex = act ? expf(v - m) : 0.f;
    float sm = ex;
#pragma unroll
    for (int o = 32; o > 0; o >>= 1) sm += __shfl_xor(sm, o, 64);
    float ls = logf(sm);
    if (act) out[(long long)n * OUT_DIM + lane] = v - m - ls;
}

extern "C" void kernel_launch(void* const* d_in, const int* in_sizes, int n_in,
                              void* d_out, int out_size, void* d_ws, size_t ws_size,
                              hipStream_t stream) {
    const float* x   = (const float*)d_in[0];
    const int*   ei  = (const int*)d_in[1];
    const float* Wl1 = (const float*)d_in[2];
    const float* bl1 = (const float*)d_in[3];
    const float* Wr1 = (const float*)d_in[4];
    const float* Wl2 = (const float*)d_in[5];
    const float* bl2 = (const float*)d_in[6];
    const float* Wr2 = (const float*)d_in[7];
    const float* Wl3 = (const float*)d_in[8];
    const float* bl3 = (const float*)d_in[9];
    const float* Wr3 = (const float*)d_in[10];
    float* out = (float*)d_out;

    const int N = in_sizes[0] / IN_DIM;  // 50000
    const int E = in_sizes[1] / 2;       // 600000
    const int* src = ei;
    const int* dst = ei + E;

    // ---- workspace layout ----
    char* w = (char*)d_ws;
    size_t off = 0;
    auto alloc = [&](size_t bytes) {
        void* p = w + off;
        off = (off + bytes + 255) & ~(size_t)255;
        return p;
    };
    ushort* xb   = (ushort*)alloc((size_t)N * IN_DIM * 2);
    ushort* M    = (ushort*)alloc((size_t)N * HID_DIM * 2);
    ushort* H1   = (ushort*)alloc((size_t)N * HID_DIM * 2);
    ushort* H2   = (ushort*)alloc((size_t)N * HID_DIM * 2);
    ushort* P3   = (ushort*)alloc((size_t)N * OUT_DIM * 2);
    float*  S3   = (float*)alloc((size_t)N * OUT_DIM * 4);
    float*  inv  = (float*)alloc((size_t)N * 4);
    int*    cnt  = (int*)alloc((size_t)N * 4);
    int*    rowptr = (int*)alloc((size_t)(N + 1) * 4);
    int*    cursor = (int*)alloc((size_t)N * 4);
    int*    srcs = (int*)alloc((size_t)E * 4);
    int*    bsum = (int*)alloc(256 * 4);
    ushort* Wl1b = (ushort*)alloc(256 * 128 * 2);
    ushort* Wr1b = (ushort*)alloc(256 * 128 * 2);
    ushort* Wl2b = (ushort*)alloc(256 * 256 * 2);
    ushort* Wr2b = (ushort*)alloc(256 * 256 * 2);
    ushort* Wl3b = (ushort*)alloc(48 * 256 * 2);
    ushort* Wr3b = (ushort*)alloc(48 * 256 * 2);

    // ---- conversions ----
    cvt_x<<<(N * IN_DIM / 4 + 255) / 256, 256, 0, stream>>>(x, xb, N * IN_DIM / 4);
    cvt_w2<<<(256 * 128 + 255) / 256, 256, 0, stream>>>(Wl1, Wr1, Wl1b, Wr1b, 256, 256, 128);
    cvt_w2<<<(256 * 256 + 255) / 256, 256, 0, stream>>>(Wl2, Wr2, Wl2b, Wr2b, 256, 256, 256);
    cvt_w2<<<(48 * 256 + 255) / 256, 256, 0, stream>>>(Wl3, Wr3, Wl3b, Wr3b, 40, 48, 256);

    // ---- CSR build (parallel 3-pass scan) ----
    const int SB = (N + SCAN_CHUNK - 1) / SCAN_CHUNK;  // 25
    hipMemsetAsync(cnt, 0, (size_t)N * sizeof(int), stream);
    hist_kernel<<<(E + 255) / 256, 256, 0, stream>>>(dst, cnt, E);
    scan_pass1<<<SB, 256, 0, stream>>>(cnt, bsum, N);
    scan_pass2<<<1, 256, 0, stream>>>(bsum, SB);
    scan_pass3<<<SB, 256, 0, stream>>>(cnt, bsum, rowptr, cursor, inv, N, E);
    fill_kernel<<<(E + 255) / 256, 256, 0, stream>>>(src, dst, cursor, srcs, E);

    const int gm = (N + 127) / 128;  // 391
    const int gg = (N + 3) / 4;

    // ---- layer 1: K=128 -> 256, relu ----
    gather_mean_bf<IN_DIM><<<gg, 256, 0, stream>>>(xb, rowptr, srcs, inv, M, N);
    sage_gemm_mfma<IN_DIM, true, true><<<dim3(gm, 4), 256, 0, stream>>>(
        M, xb, Wl1b, bl1, Wr1b, H1, N, HID_DIM);

    // ---- layer 2: K=256 -> 256, relu ----
    gather_mean_bf<HID_DIM><<<gg, 256, 0, stream>>>(H1, rowptr, srcs, inv, M, N);
    sage_gemm_mfma<HID_DIM, true, true><<<dim3(gm, 4), 256, 0, stream>>>(
        M, H1, Wl2b, bl2, Wr2b, H2, N, HID_DIM);

    // ---- layer 3 (GEMM-first): P3 = H2@Wl3^T, S3 = H2@Wr3^T, then fused agg+lsm ----
    sage_gemm_pre<HID_DIM><<<(N + 63) / 64, 256, 0, stream>>>(
        H2, Wl3b, Wr3b, P3, S3, N, OUT_DIM);
    agg_bias_lsm<<<gg, 256, 0, stream>>>(P3, S3, bl3, rowptr, srcs, inv, out, N);
}